// Round 3
// baseline (95.964 us; speedup 1.0000x reference)
//
#include <hip/hip_runtime.h>

typedef _Float16 f16x4 __attribute__((ext_vector_type(4)));
typedef float    f32x4 __attribute__((ext_vector_type(4)));

#define T_LEN   262144
#define NTAG    128
#define LCH     16                 // chunk length
#define BURN    16                 // burn-in steps
#define NSTEP   (LCH + BURN)       // 32
#define NCHUNK  (T_LEN / LCH)      // 16384
#define NWAVE   (NCHUNK / 16)      // 1024 (16 chunks per wave)
#define NSCOREB 256                // score blocks (come first in grid)
#define NFWDB   (NWAVE / 4)        // 256 forward blocks (4 indep waves each)
#define NBLK    (NSCOREB + NFWDB)  // 512

// ---------------------------------------------------------------------------
// Wave-autonomous forward algorithm. One wave owns 16 chunks (MFMA N=16).
// Per step: v = Q^T p (8 rt x 8 kt MFMAs, A=Q^T in regs), u = v*exp(emit_t),
// m = max(u) (lane-local + shfl_xor 16/32), p' = u/m (fp16 B-frags, layout
// identical to C/D), acc += log(m) when t is in the chunk's own range.
// No barriers, no LDS in the loop. logZ = sum acc + log(sum p_T-1 * e^etrans).
// ---------------------------------------------------------------------------
__global__ __launch_bounds__(256, 2) void crf_all(
    const float* __restrict__ emit, const int* __restrict__ y,
    const float* __restrict__ trans, const float* __restrict__ strans,
    const float* __restrict__ etrans, double* __restrict__ ws,
    float* __restrict__ out)
{
  if (blockIdx.x < NSCOREB) {
    // ---------------- score path ----------------
    __shared__ float sred[4];
    int idx0 = blockIdx.x * 256 + threadIdx.x;     // 0..65535
    float v = 0.f;
    for (int t = idx0; t < T_LEN - 1; t += NSCOREB * 256) {
      int yt = y[t], yn = y[t + 1];
      v += trans[yt * NTAG + yn] + emit[(size_t)t * NTAG + yt];
    }
    if (idx0 == 0) {
      int yl = y[T_LEN - 1];
      v += strans[y[0]] + etrans[yl] + emit[(size_t)(T_LEN - 1) * NTAG + yl];
    }
#pragma unroll
    for (int off = 1; off < 64; off <<= 1) v += __shfl_xor(v, off, 64);
    if ((threadIdx.x & 63) == 0) sred[threadIdx.x >> 6] = v;
    __syncthreads();
    if (threadIdx.x == 0)
      atomicAdd(&ws[1], (double)(sred[0] + sred[1] + sred[2] + sred[3]));
  } else {
    // ---------------- forward path ----------------
    const int w   = threadIdx.x >> 6;
    const int l   = threadIdx.x & 63;
    const int col = l & 15;                  // chunk column within wave
    const int grp = l >> 4;                  // lane group (k/row sub-block)
    const int gw  = (blockIdx.x - NSCOREB) * 4 + w;  // global wave id
    const int gc  = gw * 16 + col;           // this lane's global chunk

    // --- A = Q^T fragments, all 64 tiles, in registers (one-time) ---
    f16x4 a[8][8];
#pragma unroll
    for (int rt = 0; rt < 8; ++rt) {
      const int outtag = 16 * rt + col;      // A row = out-tag
#pragma unroll
      for (int kt = 0; kt < 8; ++kt) {
        f16x4 t4;
#pragma unroll
        for (int j = 0; j < 4; ++j)
          t4[j] = (_Float16)__expf(trans[(16 * kt + 4 * grp + j) * NTAG + outtag]);
        a[rt][kt] = t4;
      }
    }

    // --- init state: chunk 0 exact (alpha0 = strans + emit[0]); others p=1 ---
    f16x4 b[8];
    float acc = 0.f;
    if (gc == 0) {
      float al[8][4];
      float vm = -1e30f;
#pragma unroll
      for (int kt = 0; kt < 8; ++kt)
#pragma unroll
        for (int r = 0; r < 4; ++r) {
          int tag = 16 * kt + 4 * grp + r;
          al[kt][r] = strans[tag] + emit[tag];
          vm = fmaxf(vm, al[kt][r]);
        }
      vm = fmaxf(vm, __shfl_xor(vm, 16, 64));
      vm = fmaxf(vm, __shfl_xor(vm, 32, 64));
      acc = vm;                              // dc_0
#pragma unroll
      for (int kt = 0; kt < 8; ++kt) {
        f16x4 nb;
#pragma unroll
        for (int r = 0; r < 4; ++r) nb[r] = (_Float16)__expf(al[kt][r] - vm);
        b[kt] = nb;
      }
    } else {
#pragma unroll
      for (int kt = 0; kt < 8; ++kt) {
        f16x4 nb;
#pragma unroll
        for (int r = 0; r < 4; ++r) nb[r] = (_Float16)1.0f;
        b[kt] = nb;
      }
    }

    // --- emit prefetch: step s consumes row(s); row(s)= s+1 (chunk0) else
    //     gc*L - B + s.  Prologue loads row(0). ---
    const int row0 = (gc == 0) ? 1 : (gc * LCH - BURN);
    const float* ebase = emit + (size_t)row0 * NTAG + 4 * grp;
    float4 pf[8];
#pragma unroll
    for (int rt = 0; rt < 8; ++rt) pf[rt] = *(const float4*)(ebase + 16 * rt);
    ebase += NTAG;

    // --- main loop ---
#pragma unroll 1
    for (int s = 0; s < NSTEP; ++s) {
      // phase 1: v = Q^T p   (8 independent accumulator chains)
      f32x4 c[8];
#pragma unroll
      for (int rt = 0; rt < 8; ++rt) c[rt] = (f32x4){0.f, 0.f, 0.f, 0.f};
#pragma unroll
      for (int kt = 0; kt < 8; ++kt)
#pragma unroll
        for (int rt = 0; rt < 8; ++rt)
          c[rt] = __builtin_amdgcn_mfma_f32_16x16x16f16(a[rt][kt], b[kt], c[rt], 0, 0, 0);

      // phase 2a: E = exp(emit) (consumes pf), then issue next prefetch
      float e[8][4];
#pragma unroll
      for (int rt = 0; rt < 8; ++rt) {
        e[rt][0] = __expf(pf[rt].x);
        e[rt][1] = __expf(pf[rt].y);
        e[rt][2] = __expf(pf[rt].z);
        e[rt][3] = __expf(pf[rt].w);
      }
      if (s < NSTEP - 1) {
#pragma unroll
        for (int rt = 0; rt < 8; ++rt) pf[rt] = *(const float4*)(ebase + 16 * rt);
        ebase += NTAG;
      }

      // phase 2b: u = v*E, m = max(u), acc += log(m), p' = u/m -> fp16 B
      float u[8][4];
      float vm = -1e30f;
#pragma unroll
      for (int rt = 0; rt < 8; ++rt)
#pragma unroll
        for (int r = 0; r < 4; ++r) {
          u[rt][r] = c[rt][r] * e[rt][r];
          vm = fmaxf(vm, u[rt][r]);
        }
      vm = fmaxf(vm, __shfl_xor(vm, 16, 64));
      vm = fmaxf(vm, __shfl_xor(vm, 32, 64));
      const float lm   = __logf(vm);
      const bool  on   = (gc == 0) ? (s <= LCH - 2) : (s >= BURN);
      if (on) acc += lm;
      const float rinv = __frcp_rn(vm);
#pragma unroll
      for (int kt = 0; kt < 8; ++kt) {
        f16x4 nb;
#pragma unroll
        for (int r = 0; r < 4; ++r) nb[r] = (_Float16)(u[kt][r] * rinv);
        b[kt] = nb;
      }

      // final-state LSE (last chunk, after last step's normalize)
      if (s == NSTEP - 1 && gc == NCHUNK - 1) {
        float lv = 0.f;
#pragma unroll
        for (int rt = 0; rt < 8; ++rt)
#pragma unroll
          for (int r = 0; r < 4; ++r)
            lv += (u[rt][r] * rinv) * __expf(etrans[16 * rt + 4 * grp + r]);
        lv += __shfl_xor(lv, 16, 64);
        lv += __shfl_xor(lv, 32, 64);
        if (grp == 0) atomicAdd(&ws[2], (double)lv);
      }
    }

    // --- per-wave dc reduction: one copy per chunk (grp==0 lanes) ---
    float av = (grp == 0) ? acc : 0.f;
#pragma unroll
    for (int off = 1; off < 64; off <<= 1) av += __shfl_xor(av, off, 64);
    if (l == 0) atomicAdd(&ws[0], (double)av);
  }

  // ---------------- completion: last block computes the output ----------------
  __syncthreads();
  if (threadIdx.x == 0) {
    __threadfence();
    unsigned t = atomicAdd((unsigned*)&ws[3], 1u);
    if (t == NBLK - 1) {
      double d0 = atomicAdd(&ws[0], 0.0);   // sum dc
      double d1 = atomicAdd(&ws[1], 0.0);   // path score
      double d2 = atomicAdd(&ws[2], 0.0);   // final sum p*e^etrans
      out[0] = (float)(d0 + log(d2) - d1);
    }
  }
}

// ---------------------------------------------------------------------------
extern "C" void kernel_launch(void* const* d_in, const int* in_sizes, int n_in,
                              void* d_out, int out_size, void* d_ws, size_t ws_size,
                              hipStream_t stream)
{
  const float* emit   = (const float*)d_in[0];
  const int*   y      = (const int*)d_in[1];
  const float* trans  = (const float*)d_in[2];
  const float* strans = (const float*)d_in[3];
  const float* etrans = (const float*)d_in[4];
  float*  out = (float*)d_out;
  double* ws  = (double*)d_ws;

  hipMemsetAsync(ws, 0, 4 * sizeof(double), stream);
  crf_all<<<dim3(NBLK), dim3(256), 0, stream>>>(
      emit, y, trans, strans, etrans, ws, out);
}